// Round 1
// baseline (608.449 us; speedup 1.0000x reference)
//
#include <hip/hip_runtime.h>
#include <hip/hip_bf16.h>

#define BB 4
#define CC 256
#define NN 4096
#define CQ 32

using short8 = __attribute__((ext_vector_type(8))) short;
using f32x4  = __attribute__((ext_vector_type(4))) float;

static __device__ __forceinline__ short f2bf(float f) {
  __hip_bfloat16 h = __float2bfloat16(f);
  return *reinterpret_cast<short*>(&h);
}

// ---------------------------------------------------------------------------
// Kernel 1: QKV 1x1 convs.  rows 0..31 -> q, 32..63 -> k, 64..319 -> v.
// q stored [b][n][32] bf16, k stored [b][m][32] bf16 (both transposed via LDS),
// v stored [b][c][n] bf16 (natural layout = PV B-operand layout).
// W read via wave-uniform scalar loads (readfirstlane on wave id).
// ---------------------------------------------------------------------------
__global__ __launch_bounds__(256) void qkv_kernel(
    const float* __restrict__ x,
    const float* __restrict__ Wq, const float* __restrict__ bq,
    const float* __restrict__ Wk, const float* __restrict__ bk,
    const float* __restrict__ Wv, const float* __restrict__ bv,
    __hip_bfloat16* __restrict__ qb, __hip_bfloat16* __restrict__ kb,
    __hip_bfloat16* __restrict__ vb)
{
  const int b  = blockIdx.z;
  const int n0 = blockIdx.x * 64;
  const int r0 = blockIdx.y * 32;
  const int tid = threadIdx.x;
  const int tx  = tid & 63;
  const int tz  = __builtin_amdgcn_readfirstlane(tid >> 6);  // wave id 0..3

  __shared__ float trans[32][65];

  const float* Wp; const float* bp; int rbase;
  if (r0 == 0)       { Wp = Wq; bp = bq; rbase = 0; }
  else if (r0 == 32) { Wp = Wk; bp = bk; rbase = 0; }
  else               { Wp = Wv; bp = bv; rbase = r0 - 64; }

  float acc[8];
#pragma unroll
  for (int i = 0; i < 8; i++) acc[i] = bp[rbase + tz*8 + i];

  const float* xp = x + (size_t)b*CC*NN + n0 + tx;
  const float* wp = Wp + (size_t)(rbase + tz*8)*CC;
#pragma unroll 4
  for (int c = 0; c < CC; c++) {
    float xv = xp[(size_t)c*NN];
#pragma unroll
    for (int i = 0; i < 8; i++) acc[i] += wp[i*CC + c] * xv;
  }

  if (r0 >= 64) {
    // v: natural [c][n] layout, coalesced bf16 stores
#pragma unroll
    for (int i = 0; i < 8; i++)
      vb[((size_t)b*CC + (r0-64) + tz*8 + i)*NN + n0 + tx] = __float2bfloat16(acc[i]);
  } else {
    // q/k: transpose 32r x 64n tile -> [n][32] rows
#pragma unroll
    for (int i = 0; i < 8; i++) trans[tz*8 + i][tx] = acc[i];
    __syncthreads();
    __hip_bfloat16* dst = (r0 == 0 ? qb : kb) + (size_t)b*NN*CQ;
#pragma unroll
    for (int k2 = 0; k2 < 8; k2++) {
      int e = tid + k2*256; int nl = e >> 5, d = e & 31;
      dst[(size_t)(n0 + nl)*CQ + d] = __float2bfloat16(trans[d][nl]);
    }
  }
}

// ---------------------------------------------------------------------------
// Kernel 2: per-row softmax stats (M = rowmax, L = sum exp(S-M)) via online
// softmax over 16x16x32 MFMA score tiles.  One wave owns 16 n-rows.
// Frag layouts (measured m89/m91/m120): A[m=lane&15][k=quad*8+j],
// B^T[n=lane&15][k=quad*8+j], D[row=quad*4+reg][col=lane&15].
// ---------------------------------------------------------------------------
__global__ __launch_bounds__(256) void stats_kernel(
    const __hip_bfloat16* __restrict__ qb, const __hip_bfloat16* __restrict__ kb,
    float* __restrict__ Mrow, float* __restrict__ Lrow)
{
  const int b = blockIdx.y;
  const int tid = threadIdx.x;
  const int w = tid >> 6;
  const int lane = tid & 63;
  const int l15 = lane & 15, quad = lane >> 4;
  const int nw = blockIdx.x*64 + w*16;

  const short* qbase = reinterpret_cast<const short*>(qb) + (size_t)b*NN*CQ;
  const short* kbase = reinterpret_cast<const short*>(kb) + (size_t)b*NN*CQ;
  short8 aq = *reinterpret_cast<const short8*>(qbase + (size_t)(nw + l15)*CQ + quad*8);

  float M[4], L[4];
#pragma unroll
  for (int r = 0; r < 4; r++) { M[r] = -1e30f; L[r] = 0.0f; }

  for (int m0 = 0; m0 < NN; m0 += 32) {
    short8 b0 = *reinterpret_cast<const short8*>(kbase + (size_t)(m0      + l15)*CQ + quad*8);
    short8 b1 = *reinterpret_cast<const short8*>(kbase + (size_t)(m0 + 16 + l15)*CQ + quad*8);
    f32x4 z = {0.f, 0.f, 0.f, 0.f};
    f32x4 S0 = __builtin_amdgcn_mfma_f32_16x16x32_bf16(aq, b0, z, 0, 0, 0);
    f32x4 S1 = __builtin_amdgcn_mfma_f32_16x16x32_bf16(aq, b1, z, 0, 0, 0);
#pragma unroll
    for (int r = 0; r < 4; r++) {
      float mx = fmaxf(S0[r], S1[r]);
      mx = fmaxf(mx, __shfl_xor(mx, 1));
      mx = fmaxf(mx, __shfl_xor(mx, 2));
      mx = fmaxf(mx, __shfl_xor(mx, 4));
      mx = fmaxf(mx, __shfl_xor(mx, 8));   // uniform across the quad's 16 lanes
      float Mn = fmaxf(M[r], mx);
      float s = __expf(S0[r] - Mn) + __expf(S1[r] - Mn);
      s += __shfl_xor(s, 1);
      s += __shfl_xor(s, 2);
      s += __shfl_xor(s, 4);
      s += __shfl_xor(s, 8);
      L[r] = L[r] * __expf(M[r] - Mn) + s;
      M[r] = Mn;
    }
  }
  if (l15 == 0) {
#pragma unroll
    for (int r = 0; r < 4; r++) {
      int n = nw + quad*4 + r;
      Mrow[b*NN + n] = M[r];
      Lrow[b*NN + n] = L[r];
    }
  }
}

// ---------------------------------------------------------------------------
// Kernel 3: O = softmax(QK^T) V, epilogue gamma*O + x.
// Block = 64 n-rows (4 waves x 16) x all 256 c.  m-loop in tiles of 32:
// recompute S (bit-identical to kernel 2), P = exp(S-M)/L -> bf16 via LDS
// round-trip (C/D layout -> A layout), then 16 PV MFMAs against LDS V tile.
// ---------------------------------------------------------------------------
__global__ __launch_bounds__(256) void attn_kernel(
    const __hip_bfloat16* __restrict__ qb, const __hip_bfloat16* __restrict__ kb,
    const __hip_bfloat16* __restrict__ vb,
    const float* __restrict__ Mrow, const float* __restrict__ Lrow,
    const float* __restrict__ x, const float* __restrict__ gamma,
    float* __restrict__ out)
{
  const int b = blockIdx.y;
  const int n0 = blockIdx.x*64;
  const int tid = threadIdx.x;
  const int w = tid >> 6;
  const int lane = tid & 63;
  const int l15 = lane & 15, quad = lane >> 4;
  const int nw = n0 + w*16;

  __shared__ short Vs[256][40];   // [c][m] tile, pad 32->40 (2-way max on b128)
  __shared__ short Ps[64][40];    // per-wave 16-row P regions, [n][m]
  __shared__ float Es[16][67];    // epilogue transpose chunk

  const short* qbase = reinterpret_cast<const short*>(qb) + (size_t)b*NN*CQ;
  const short* kbase = reinterpret_cast<const short*>(kb) + (size_t)b*NN*CQ;
  const short* vbase = reinterpret_cast<const short*>(vb) + (size_t)b*CC*NN;

  short8 aq = *reinterpret_cast<const short8*>(qbase + (size_t)(nw + l15)*CQ + quad*8);

  float M[4], Li[4];
#pragma unroll
  for (int r = 0; r < 4; r++) {
    int n = nw + quad*4 + r;
    M[r]  = Mrow[b*NN + n];
    Li[r] = 1.0f / Lrow[b*NN + n];
  }

  f32x4 acc[16];
#pragma unroll
  for (int cc = 0; cc < 16; cc++) acc[cc] = (f32x4){0.f,0.f,0.f,0.f};

  for (int m0 = 0; m0 < NN; m0 += 32) {
    __syncthreads();
    // stage V[0:256][m0:m0+32] -> Vs (16B vector loads, coalesced 64B rows)
#pragma unroll
    for (int k2 = 0; k2 < 4; k2++) {
      int e = tid + k2*256;
      int cv = e >> 2, mb = e & 3;
      *reinterpret_cast<short8*>(&Vs[cv][mb*8]) =
          *reinterpret_cast<const short8*>(vbase + (size_t)cv*NN + m0 + mb*8);
    }
    __syncthreads();

    short8 b0 = *reinterpret_cast<const short8*>(kbase + (size_t)(m0      + l15)*CQ + quad*8);
    short8 b1 = *reinterpret_cast<const short8*>(kbase + (size_t)(m0 + 16 + l15)*CQ + quad*8);
    f32x4 z = {0.f,0.f,0.f,0.f};
    f32x4 S0 = __builtin_amdgcn_mfma_f32_16x16x32_bf16(aq, b0, z, 0, 0, 0);
    f32x4 S1 = __builtin_amdgcn_mfma_f32_16x16x32_bf16(aq, b1, z, 0, 0, 0);

    // P = exp(S - M) / L in bf16, written in [n][m] rows (wave-private region)
#pragma unroll
    for (int r = 0; r < 4; r++) {
      int rowp = w*16 + quad*4 + r;
      Ps[rowp][l15]      = f2bf(__expf(S0[r] - M[r]) * Li[r]);
      Ps[rowp][16 + l15] = f2bf(__expf(S1[r] - M[r]) * Li[r]);
    }
    // re-read as A-operand frag (same wave wrote all 16 rows; LDS in-order)
    short8 ap = *reinterpret_cast<const short8*>(&Ps[w*16 + l15][quad*8]);
#pragma unroll
    for (int cc = 0; cc < 16; cc++) {
      short8 bv8 = *reinterpret_cast<const short8*>(&Vs[cc*16 + l15][quad*8]);
      acc[cc] = __builtin_amdgcn_mfma_f32_16x16x32_bf16(ap, bv8, acc[cc], 0, 0, 0);
    }
  }

  // epilogue: out[b][c][n] = gamma*O[n][c] + x[b][c][n], transpose via LDS
  const float g = gamma[0];
#pragma unroll 1
  for (int cc = 0; cc < 16; cc++) {
    __syncthreads();
#pragma unroll
    for (int r = 0; r < 4; r++) Es[l15][w*16 + quad*4 + r] = acc[cc][r];
    __syncthreads();
#pragma unroll
    for (int k2 = 0; k2 < 4; k2++) {
      int e = tid + k2*256;
      int cl = e >> 6, nn2 = e & 63;
      size_t idx = ((size_t)b*CC + cc*16 + cl)*NN + n0 + nn2;
      out[idx] = g * Es[cl][nn2] + x[idx];
    }
  }
}

// ---------------------------------------------------------------------------
extern "C" void kernel_launch(void* const* d_in, const int* in_sizes, int n_in,
                              void* d_out, int out_size, void* d_ws, size_t ws_size,
                              hipStream_t stream) {
  const float* x     = (const float*)d_in[0];
  const float* Wq    = (const float*)d_in[1];
  const float* bq    = (const float*)d_in[2];
  const float* Wk    = (const float*)d_in[3];
  const float* bk    = (const float*)d_in[4];
  const float* Wv    = (const float*)d_in[5];
  const float* bv    = (const float*)d_in[6];
  const float* gamma = (const float*)d_in[7];
  float* out = (float*)d_out;

  // workspace layout (needs ~10.6 MB)
  char* ws = (char*)d_ws;
  if (ws_size < (11u << 20)) return;  // fail loudly rather than corrupt
  __hip_bfloat16* qb = (__hip_bfloat16*)(ws);                 // [B][N][32]  1 MB
  __hip_bfloat16* kb = (__hip_bfloat16*)(ws + (1u << 20));    // [B][N][32]  1 MB
  __hip_bfloat16* vb = (__hip_bfloat16*)(ws + (2u << 20));    // [B][C][N]   8 MB
  float* Mrow = (float*)(ws + (10u << 20));                   // [B][N]
  float* Lrow = (float*)(ws + (10u << 20) + (1u << 18));      // [B][N]

  qkv_kernel<<<dim3(64, 10, 4), 256, 0, stream>>>(x, Wq, bq, Wk, bk, Wv, bv, qb, kb, vb);
  stats_kernel<<<dim3(64, 4), 256, 0, stream>>>(qb, kb, Mrow, Lrow);
  attn_kernel<<<dim3(64, 4), 256, 0, stream>>>(qb, kb, vb, Mrow, Lrow, x, gamma, out);
}

// Round 2
// 232.719 us; speedup vs baseline: 2.6145x; 2.6145x over previous
//
#include <hip/hip_runtime.h>
#include <hip/hip_bf16.h>

#define CC 256
#define NN 4096
#define CQ 32
#define LOG2E 1.4426950408889634f

using short8 = __attribute__((ext_vector_type(8))) short;
using f32x4  = __attribute__((ext_vector_type(4))) float;

static __device__ __forceinline__ short f2bf(float f) {
  __hip_bfloat16 h = __float2bfloat16(f);
  return *reinterpret_cast<short*>(&h);
}

// ---------------------------------------------------------------------------
// Kernel 1: QKV 1x1 convs.  rows 0..31 -> q (pre-scaled by log2e), 32..63 -> k,
// 64..319 -> v.  q stored [b][n][32] bf16, k stored [b][m][32] bf16, v stored
// [b][c][n] bf16 (natural layout = PV B-operand layout).
// ---------------------------------------------------------------------------
__global__ __launch_bounds__(256) void qkv_kernel(
    const float* __restrict__ x,
    const float* __restrict__ Wq, const float* __restrict__ bq,
    const float* __restrict__ Wk, const float* __restrict__ bk,
    const float* __restrict__ Wv, const float* __restrict__ bv,
    __hip_bfloat16* __restrict__ qb, __hip_bfloat16* __restrict__ kb,
    __hip_bfloat16* __restrict__ vb)
{
  const int b  = blockIdx.z;
  const int n0 = blockIdx.x * 64;
  const int r0 = blockIdx.y * 32;
  const int tid = threadIdx.x;
  const int tx  = tid & 63;
  const int tz  = __builtin_amdgcn_readfirstlane(tid >> 6);  // wave id 0..3

  __shared__ float trans[32][65];

  const float* Wp; const float* bp; int rbase;
  if (r0 == 0)       { Wp = Wq; bp = bq; rbase = 0; }
  else if (r0 == 32) { Wp = Wk; bp = bk; rbase = 0; }
  else               { Wp = Wv; bp = bv; rbase = r0 - 64; }

  float acc[8];
#pragma unroll
  for (int i = 0; i < 8; i++) acc[i] = bp[rbase + tz*8 + i];

  const float* xp = x + (size_t)b*CC*NN + n0 + tx;
  const float* wp = Wp + (size_t)(rbase + tz*8)*CC;
#pragma unroll 4
  for (int c = 0; c < CC; c++) {
    float xv = xp[(size_t)c*NN];
#pragma unroll
    for (int i = 0; i < 8; i++) acc[i] += wp[i*CC + c] * xv;
  }

  if (r0 >= 64) {
#pragma unroll
    for (int i = 0; i < 8; i++)
      vb[((size_t)b*CC + (r0-64) + tz*8 + i)*NN + n0 + tx] = __float2bfloat16(acc[i]);
  } else {
#pragma unroll
    for (int i = 0; i < 8; i++) trans[tz*8 + i][tx] = acc[i];
    __syncthreads();
    __hip_bfloat16* dst = (r0 == 0 ? qb : kb) + (size_t)b*NN*CQ;
    const float sc = (r0 == 0) ? LOG2E : 1.0f;  // fold log2e into q
#pragma unroll
    for (int k2 = 0; k2 < 8; k2++) {
      int e = tid + k2*256; int nl = e >> 5, d = e & 31;
      dst[(size_t)(n0 + nl)*CQ + d] = __float2bfloat16(trans[d][nl] * sc);
    }
  }
}

// ---------------------------------------------------------------------------
// Kernel 2 (fused): O = softmax(QK^T) V, epilogue gamma*O + x.
// No stats pass: with q pre-scaled by log2e, P = exp2(S') unnormalized is
// safe in fp32/bf16 (|S'| < ~50 << 127), so softmax = P / sum(P) exactly.
// Block = 64 n-rows (4 waves x 16) x all 256 c.  Double-buffered V staging:
// prefetch tile t+1 V into regs + K frags at loop top, compute tile t,
// ds_write next buffer, ONE barrier per tile (lgkm-only drain).
// ---------------------------------------------------------------------------
__global__ __launch_bounds__(256) void attn_kernel(
    const __hip_bfloat16* __restrict__ qb, const __hip_bfloat16* __restrict__ kb,
    const __hip_bfloat16* __restrict__ vb,
    const float* __restrict__ x, const float* __restrict__ gamma,
    float* __restrict__ out)
{
  const int b = blockIdx.y;
  const int n0 = blockIdx.x*64;
  const int tid = threadIdx.x;
  const int w = tid >> 6;
  const int lane = tid & 63;
  const int l15 = lane & 15, quad = lane >> 4;
  const int nw = n0 + w*16;

  __shared__ short Vs[2][256][40];  // [buf][c][m], pad 32->40: 2-way max (free)
  __shared__ short Ps[64][40];      // wave-private 16-row P regions, [n][m]
  __shared__ float Es[4][16][67];   // epilogue transpose, 4 c-groups/round

  const short* qbase = reinterpret_cast<const short*>(qb) + (size_t)b*NN*CQ;
  const short* kbase = reinterpret_cast<const short*>(kb) + (size_t)b*NN*CQ;
  const short* vbase = reinterpret_cast<const short*>(vb) + (size_t)b*CC*NN;

  short8 aq = *reinterpret_cast<const short8*>(qbase + (size_t)(nw + l15)*CQ + quad*8);

  const int cvb = tid >> 2, mb = tid & 3;  // V staging: 4 granules/thread

  // preload tile 0
#pragma unroll
  for (int k2 = 0; k2 < 4; k2++) {
    int cv = cvb + k2*64;
    *reinterpret_cast<short8*>(&Vs[0][cv][mb*8]) =
        *reinterpret_cast<const short8*>(vbase + (size_t)cv*NN + mb*8);
  }
  short8 kf0 = *reinterpret_cast<const short8*>(kbase + (size_t)(l15)*CQ + quad*8);
  short8 kf1 = *reinterpret_cast<const short8*>(kbase + (size_t)(16 + l15)*CQ + quad*8);

  f32x4 acc[16];
#pragma unroll
  for (int cc = 0; cc < 16; cc++) acc[cc] = (f32x4){0.f,0.f,0.f,0.f};
  float lsum[4] = {0.f, 0.f, 0.f, 0.f};

  __syncthreads();

  for (int t = 0; t < 128; t++) {
    const int cur = t & 1;
    const int mnext = t*32 + 32;

    // prefetch next tile (global -> regs); latency hidden under compute
    short8 nv0, nv1, nv2, nv3, nk0, nk1;
    if (t < 127) {
      nv0 = *reinterpret_cast<const short8*>(vbase + (size_t)(cvb      )*NN + mnext + mb*8);
      nv1 = *reinterpret_cast<const short8*>(vbase + (size_t)(cvb +  64)*NN + mnext + mb*8);
      nv2 = *reinterpret_cast<const short8*>(vbase + (size_t)(cvb + 128)*NN + mnext + mb*8);
      nv3 = *reinterpret_cast<const short8*>(vbase + (size_t)(cvb + 192)*NN + mnext + mb*8);
      nk0 = *reinterpret_cast<const short8*>(kbase + (size_t)(mnext      + l15)*CQ + quad*8);
      nk1 = *reinterpret_cast<const short8*>(kbase + (size_t)(mnext + 16 + l15)*CQ + quad*8);
    }

    // S' = log2e * q k^T  (16 n-rows x 32 m)
    f32x4 z = {0.f,0.f,0.f,0.f};
    f32x4 S0 = __builtin_amdgcn_mfma_f32_16x16x32_bf16(aq, kf0, z, 0, 0, 0);
    f32x4 S1 = __builtin_amdgcn_mfma_f32_16x16x32_bf16(aq, kf1, z, 0, 0, 0);

    // unnormalized P = exp2(S'), accumulate row sums
    const int rowp = w*16 + quad*4;
#pragma unroll
    for (int r = 0; r < 4; r++) {
      float e0 = __builtin_amdgcn_exp2f(S0[r]);
      float e1 = __builtin_amdgcn_exp2f(S1[r]);
      lsum[r] += e0 + e1;
      Ps[rowp + r][l15]      = f2bf(e0);
      Ps[rowp + r][16 + l15] = f2bf(e1);
    }
    // LDS round-trip: C/D layout -> A-operand layout (wave-private rows)
    short8 ap = *reinterpret_cast<const short8*>(&Ps[w*16 + l15][quad*8]);

    // O += P V^T over this m-tile
#pragma unroll
    for (int cc = 0; cc < 16; cc++) {
      short8 bv8 = *reinterpret_cast<const short8*>(&Vs[cur][cc*16 + l15][quad*8]);
      acc[cc] = __builtin_amdgcn_mfma_f32_16x16x32_bf16(ap, bv8, acc[cc], 0, 0, 0);
    }

    // write prefetched V tile into the other buffer
    if (t < 127) {
      *reinterpret_cast<short8*>(&Vs[cur^1][cvb      ][mb*8]) = nv0;
      *reinterpret_cast<short8*>(&Vs[cur^1][cvb +  64][mb*8]) = nv1;
      *reinterpret_cast<short8*>(&Vs[cur^1][cvb + 128][mb*8]) = nv2;
      *reinterpret_cast<short8*>(&Vs[cur^1][cvb + 192][mb*8]) = nv3;
      kf0 = nk0; kf1 = nk1;
    }
    __syncthreads();
  }

  // row sums -> 1/l (reduce across the quad's 16 lanes)
  float Li[4];
#pragma unroll
  for (int r = 0; r < 4; r++) {
    float s = lsum[r];
    s += __shfl_xor(s, 1);
    s += __shfl_xor(s, 2);
    s += __shfl_xor(s, 4);
    s += __shfl_xor(s, 8);
    Li[r] = 1.0f / s;
  }

  // epilogue: out[b][c][n] = gamma*O[n][c]/l[n] + x[b][c][n]
  const float g = gamma[0];
#pragma unroll
  for (int cg = 0; cg < 4; cg++) {
    __syncthreads();
#pragma unroll
    for (int c2 = 0; c2 < 4; c2++)
#pragma unroll
      for (int r = 0; r < 4; r++)
        Es[c2][l15][w*16 + quad*4 + r] = acc[cg*4 + c2][r] * Li[r];
    __syncthreads();
#pragma unroll
    for (int k2 = 0; k2 < 16; k2++) {
      int e = tid + k2*256;
      int row = e >> 6, nn2 = e & 63;    // row 0..63 within this c-group
      size_t idx = ((size_t)b*CC + cg*64 + row)*NN + n0 + nn2;
      out[idx] = g * Es[row >> 4][row & 15][nn2] + x[idx];
    }
  }
}

// ---------------------------------------------------------------------------
extern "C" void kernel_launch(void* const* d_in, const int* in_sizes, int n_in,
                              void* d_out, int out_size, void* d_ws, size_t ws_size,
                              hipStream_t stream) {
  const float* x     = (const float*)d_in[0];
  const float* Wq    = (const float*)d_in[1];
  const float* bq    = (const float*)d_in[2];
  const float* Wk    = (const float*)d_in[3];
  const float* bk    = (const float*)d_in[4];
  const float* Wv    = (const float*)d_in[5];
  const float* bv    = (const float*)d_in[6];
  const float* gamma = (const float*)d_in[7];
  float* out = (float*)d_out;

  char* ws = (char*)d_ws;
  if (ws_size < (10u << 20)) return;
  __hip_bfloat16* qb = (__hip_bfloat16*)(ws);                 // [B][N][32]  1 MB
  __hip_bfloat16* kb = (__hip_bfloat16*)(ws + (1u << 20));    // [B][N][32]  1 MB
  __hip_bfloat16* vb = (__hip_bfloat16*)(ws + (2u << 20));    // [B][C][N]   8 MB

  qkv_kernel<<<dim3(64, 10, 4), 256, 0, stream>>>(x, Wq, bq, Wk, bk, Wv, bv, qb, kb, vb);
  attn_kernel<<<dim3(64, 4), 256, 0, stream>>>(qb, kb, vb, x, gamma, out);
}